// Round 1
// baseline (15.525 us; speedup 1.0000x reference)
//
#include <hip/hip_runtime.h>

// Problem constants (from reference)
constexpr int   B  = 32, N = 17;          // batch, keypoints
constexpr int   BN = B * N;               // 544
constexpr int   H = 128, W = 128, HW = H * W;
constexpr float L_IMG   = 512.0f;
constexpr float STRIDE  = 4.0f;           // L // W = 512/128
constexpr float START   = STRIDE / 2.0f - 0.5f;   // 1.5
constexpr float INV2SG2 = 1.0f / (2.0f * 8.0f * 8.0f); // 1/(2*sigma^2)
constexpr float TRUNCV  = 4.6052f;

// Kernel 1: one block per (b,n). 256 threads, 64 px/thread via float4.
__global__ __launch_bounds__(256)
void heatmap_loss_per_kp(const float* __restrict__ pred,   // [BN, HW]
                         const float* __restrict__ labels, // [BN, 2]
                         const float* __restrict__ mask,   // [BN]
                         float* __restrict__ ws_loss)      // [BN]
{
    const int bn = blockIdx.x;
    const int t  = threadIdx.x;

    const float lx = labels[bn * 2 + 0];
    const float ly = labels[bn * 2 + 1];
    const float cx = fminf(fmaxf((lx * 0.5f + 0.5f) * L_IMG, 0.0f), L_IMG - 1.0f);
    const float cy = fminf(fmaxf((ly * 0.5f + 0.5f) * L_IMG, 0.0f), L_IMG - 1.0f);

    const float4* p4 = reinterpret_cast<const float4*>(pred + (size_t)bn * HW);

    float acc = 0.0f;
    #pragma unroll
    for (int j = 0; j < 16; ++j) {
        const int f4 = j * 256 + t;           // float4 index in [0,4096)
        const float4 v = p4[f4];
        const int e = f4 * 4;                 // element index (multiple of 4)
        const int h = e >> 7;                 // row
        const int w = e & 127;                // col of first element (multiple of 4)
        const float gy  = START + STRIDE * (float)h;
        const float dy  = gy - cy;
        const float dy2 = dy * dy;

        const float pv[4] = { v.x, v.y, v.z, v.w };
        #pragma unroll
        for (int k = 0; k < 4; ++k) {
            const float gx   = START + STRIDE * (float)(w + k);
            const float dx   = gx - cx;
            const float d2   = fmaf(dx, dx, dy2);
            const float expo = d2 * INV2SG2;
            const float gt   = (expo > TRUNCV) ? 0.0f : expf(-expo);
            const float diff = pv[k] - gt;
            acc = fmaf(diff, diff, acc);
        }
    }

    // wave (64-lane) shuffle reduce
    #pragma unroll
    for (int off = 32; off > 0; off >>= 1)
        acc += __shfl_down(acc, off, 64);

    __shared__ float sacc[4];
    const int wave = t >> 6;
    if ((t & 63) == 0) sacc[wave] = acc;
    __syncthreads();

    if (t == 0) {
        const float s     = sacc[0] + sacc[1] + sacc[2] + sacc[3];
        const float valid = (mask[bn] > 0.0f) ? 1.0f : 0.0f;
        ws_loss[bn] = s * (1.0f / (float)HW) * valid;
    }
}

// Kernel 2: single block, deterministic final reduction over 544 entries.
__global__ __launch_bounds__(256)
void heatmap_loss_final(const float* __restrict__ ws_loss, // [BN]
                        const float* __restrict__ mask,    // [BN]
                        float* __restrict__ out)           // [1]
{
    const int t = threadIdx.x;
    float tot = 0.0f, nv = 0.0f;
    for (int i = t; i < BN; i += 256) {
        tot += ws_loss[i];
        nv  += mask[i];
    }
    #pragma unroll
    for (int off = 32; off > 0; off >>= 1) {
        tot += __shfl_down(tot, off, 64);
        nv  += __shfl_down(nv,  off, 64);
    }
    __shared__ float st[4], sn[4];
    const int wave = t >> 6;
    if ((t & 63) == 0) { st[wave] = tot; sn[wave] = nv; }
    __syncthreads();
    if (t == 0) {
        const float T  = st[0] + st[1] + st[2] + st[3];
        const float NV = sn[0] + sn[1] + sn[2] + sn[3];
        out[0] = (NV > 0.0f) ? (T / fmaxf(NV, 1.0f)) : 0.0f;
    }
}

extern "C" void kernel_launch(void* const* d_in, const int* in_sizes, int n_in,
                              void* d_out, int out_size, void* d_ws, size_t ws_size,
                              hipStream_t stream) {
    const float* pred   = (const float*)d_in[0]; // [B,N,H,W]
    const float* labels = (const float*)d_in[1]; // [B,N,2]
    const float* mask   = (const float*)d_in[2]; // [B,N]
    float* out = (float*)d_out;
    float* ws  = (float*)d_ws;                   // needs BN*4 = 2176 bytes

    heatmap_loss_per_kp<<<BN, 256, 0, stream>>>(pred, labels, mask, ws);
    heatmap_loss_final<<<1, 256, 0, stream>>>(ws, mask, out);
}

// Round 2
// 13.285 us; speedup vs baseline: 1.1686x; 1.1686x over previous
//
#include <hip/hip_runtime.h>

// Problem constants (from reference)
constexpr int   B  = 32, N = 17;          // batch, keypoints
constexpr int   BN = B * N;               // 544
constexpr int   H = 128, W = 128, HW = H * W;
constexpr int   BLOCKS_PER_BN = 4;        // 4096 px per block
constexpr int   NPART = BN * BLOCKS_PER_BN; // 2176 partials
constexpr float L_IMG   = 512.0f;
constexpr float STRIDE  = 4.0f;           // L // W
constexpr float START   = STRIDE / 2.0f - 0.5f;   // 1.5
constexpr float INV2SG2 = 1.0f / (2.0f * 8.0f * 8.0f);
constexpr float TRUNCV  = 4.6052f;

// Kernel 1: 4 blocks per (b,n). 256 threads, 16 px/thread via float4.
__global__ __launch_bounds__(256)
void heatmap_loss_per_kp(const float* __restrict__ pred,   // [BN, HW]
                         const float* __restrict__ labels, // [BN, 2]
                         const float* __restrict__ mask,   // [BN]
                         float* __restrict__ part)         // [NPART]
{
    const int bid = blockIdx.x;
    const int bn  = bid >> 2;
    const int q   = bid & 3;
    const int t   = threadIdx.x;

    const float lx = labels[bn * 2 + 0];
    const float ly = labels[bn * 2 + 1];
    const float cx = fminf(fmaxf((lx * 0.5f + 0.5f) * L_IMG, 0.0f), L_IMG - 1.0f);
    const float cy = fminf(fmaxf((ly * 0.5f + 0.5f) * L_IMG, 0.0f), L_IMG - 1.0f);

    const float4* p4 = reinterpret_cast<const float4*>(pred + (size_t)bn * HW) + q * 1024;

    float acc = 0.0f;
    #pragma unroll
    for (int j = 0; j < 4; ++j) {
        const int f4 = j * 256 + t;           // float4 index within quarter [0,1024)
        const float4 v = p4[f4];
        const int e = (q * 1024 + f4) * 4;    // element index within bn
        const int h = e >> 7;                 // row
        const int w = e & 127;                // col of first element
        const float dy  = fmaf(STRIDE, (float)h, START) - cy;
        const float dy2 = dy * dy;

        const float pv[4] = { v.x, v.y, v.z, v.w };
        #pragma unroll
        for (int k = 0; k < 4; ++k) {
            const float dx   = fmaf(STRIDE, (float)(w + k), START) - cx;
            const float d2   = fmaf(dx, dx, dy2);
            const float expo = d2 * INV2SG2;
            const float gt   = (expo > TRUNCV) ? 0.0f : __expf(-expo);
            const float diff = pv[k] - gt;
            acc = fmaf(diff, diff, acc);
        }
    }

    // wave (64-lane) shuffle reduce
    #pragma unroll
    for (int off = 32; off > 0; off >>= 1)
        acc += __shfl_down(acc, off, 64);

    __shared__ float sacc[4];
    const int wave = t >> 6;
    if ((t & 63) == 0) sacc[wave] = acc;
    __syncthreads();

    if (t == 0) {
        const float s     = sacc[0] + sacc[1] + sacc[2] + sacc[3];
        const float valid = (mask[bn] > 0.0f) ? 1.0f : 0.0f;
        part[bid] = s * (1.0f / (float)HW) * valid;
    }
}

// Kernel 2: single block, deterministic final reduction.
__global__ __launch_bounds__(256)
void heatmap_loss_final(const float* __restrict__ part,    // [NPART]
                        const float* __restrict__ mask,    // [BN]
                        float* __restrict__ out)           // [1]
{
    const int t = threadIdx.x;
    float tot = 0.0f, nv = 0.0f;
    #pragma unroll
    for (int i = t; i < NPART; i += 256) tot += part[i];
    for (int i = t; i < BN;    i += 256) nv  += mask[i];
    #pragma unroll
    for (int off = 32; off > 0; off >>= 1) {
        tot += __shfl_down(tot, off, 64);
        nv  += __shfl_down(nv,  off, 64);
    }
    __shared__ float st[4], sn[4];
    const int wave = t >> 6;
    if ((t & 63) == 0) { st[wave] = tot; sn[wave] = nv; }
    __syncthreads();
    if (t == 0) {
        const float T  = st[0] + st[1] + st[2] + st[3];
        const float NV = sn[0] + sn[1] + sn[2] + sn[3];
        out[0] = (NV > 0.0f) ? (T / fmaxf(NV, 1.0f)) : 0.0f;
    }
}

extern "C" void kernel_launch(void* const* d_in, const int* in_sizes, int n_in,
                              void* d_out, int out_size, void* d_ws, size_t ws_size,
                              hipStream_t stream) {
    const float* pred   = (const float*)d_in[0]; // [B,N,H,W]
    const float* labels = (const float*)d_in[1]; // [B,N,2]
    const float* mask   = (const float*)d_in[2]; // [B,N]
    float* out = (float*)d_out;
    float* ws  = (float*)d_ws;                   // needs NPART*4 = 8704 bytes

    heatmap_loss_per_kp<<<NPART, 256, 0, stream>>>(pred, labels, mask, ws);
    heatmap_loss_final<<<1, 256, 0, stream>>>(ws, mask, out);
}

// Round 3
// 13.115 us; speedup vs baseline: 1.1838x; 1.0130x over previous
//
#include <hip/hip_runtime.h>

// Problem constants (from reference)
constexpr int   B  = 32, N = 17;          // batch, keypoints
constexpr int   BN = B * N;               // 544
constexpr int   H = 128, W = 128, HW = H * W;
constexpr int   BLOCKS_PER_BN = 4;        // 4096 px per block
constexpr int   NPART = BN * BLOCKS_PER_BN; // 2176 partials
constexpr float L_IMG   = 512.0f;
constexpr float STRIDE  = 4.0f;           // L // W
constexpr float START   = STRIDE / 2.0f - 0.5f;   // 1.5
constexpr float INV2SG2 = 1.0f / (2.0f * 8.0f * 8.0f);
constexpr float TRUNCV  = 4.6052f;

// Kernel 1: 4 blocks per (b,n). Masked-out keypoints never touch the
// output (loss is multiplied by valid), so skip their 64 KB entirely:
// ~50% of mask is 0 -> dominant HBM/L3 traffic halves.
__global__ __launch_bounds__(256)
void heatmap_loss_per_kp(const float* __restrict__ pred,   // [BN, HW]
                         const float* __restrict__ labels, // [BN, 2]
                         const float* __restrict__ mask,   // [BN]
                         float* __restrict__ part)         // [NPART]
{
    const int bid = blockIdx.x;
    const int bn  = bid >> 2;
    const int q   = bid & 3;
    const int t   = threadIdx.x;

    // Block-uniform early exit for masked-out keypoints.
    if (mask[bn] <= 0.0f) {
        if (t == 0) part[bid] = 0.0f;   // fresh write every call (no stale ws state)
        return;
    }

    const float lx = labels[bn * 2 + 0];
    const float ly = labels[bn * 2 + 1];
    const float cx = fminf(fmaxf((lx * 0.5f + 0.5f) * L_IMG, 0.0f), L_IMG - 1.0f);
    const float cy = fminf(fmaxf((ly * 0.5f + 0.5f) * L_IMG, 0.0f), L_IMG - 1.0f);

    const float4* p4 = reinterpret_cast<const float4*>(pred + (size_t)bn * HW) + q * 1024;

    float acc = 0.0f;
    #pragma unroll
    for (int j = 0; j < 4; ++j) {
        const int f4 = j * 256 + t;           // float4 index within quarter [0,1024)
        const float4 v = p4[f4];
        const int e = (q * 1024 + f4) * 4;    // element index within bn
        const int h = e >> 7;                 // row
        const int w = e & 127;                // col of first element
        const float dy  = fmaf(STRIDE, (float)h, START) - cy;
        const float dy2 = dy * dy;

        const float pv[4] = { v.x, v.y, v.z, v.w };
        #pragma unroll
        for (int k = 0; k < 4; ++k) {
            const float dx   = fmaf(STRIDE, (float)(w + k), START) - cx;
            const float d2   = fmaf(dx, dx, dy2);
            const float expo = d2 * INV2SG2;
            const float gt   = (expo > TRUNCV) ? 0.0f : __expf(-expo);
            const float diff = pv[k] - gt;
            acc = fmaf(diff, diff, acc);
        }
    }

    // wave (64-lane) shuffle reduce
    #pragma unroll
    for (int off = 32; off > 0; off >>= 1)
        acc += __shfl_down(acc, off, 64);

    __shared__ float sacc[4];
    const int wave = t >> 6;
    if ((t & 63) == 0) sacc[wave] = acc;
    __syncthreads();

    if (t == 0)
        part[bid] = (sacc[0] + sacc[1] + sacc[2] + sacc[3]) * (1.0f / (float)HW);
}

// Kernel 2: single block, deterministic final reduction.
__global__ __launch_bounds__(256)
void heatmap_loss_final(const float* __restrict__ part,    // [NPART]
                        const float* __restrict__ mask,    // [BN]
                        float* __restrict__ out)           // [1]
{
    const int t = threadIdx.x;
    float tot = 0.0f, nv = 0.0f;
    #pragma unroll
    for (int i = t; i < NPART; i += 256) tot += part[i];
    for (int i = t; i < BN;    i += 256) nv  += mask[i];
    #pragma unroll
    for (int off = 32; off > 0; off >>= 1) {
        tot += __shfl_down(tot, off, 64);
        nv  += __shfl_down(nv,  off, 64);
    }
    __shared__ float st[4], sn[4];
    const int wave = t >> 6;
    if ((t & 63) == 0) { st[wave] = tot; sn[wave] = nv; }
    __syncthreads();
    if (t == 0) {
        const float T  = st[0] + st[1] + st[2] + st[3];
        const float NV = sn[0] + sn[1] + sn[2] + sn[3];
        out[0] = (NV > 0.0f) ? (T / fmaxf(NV, 1.0f)) : 0.0f;
    }
}

extern "C" void kernel_launch(void* const* d_in, const int* in_sizes, int n_in,
                              void* d_out, int out_size, void* d_ws, size_t ws_size,
                              hipStream_t stream) {
    const float* pred   = (const float*)d_in[0]; // [B,N,H,W]
    const float* labels = (const float*)d_in[1]; // [B,N,2]
    const float* mask   = (const float*)d_in[2]; // [B,N]
    float* out = (float*)d_out;
    float* ws  = (float*)d_ws;                   // needs NPART*4 = 8704 bytes

    heatmap_loss_per_kp<<<NPART, 256, 0, stream>>>(pred, labels, mask, ws);
    heatmap_loss_final<<<1, 256, 0, stream>>>(ws, mask, out);
}